// Round 1
// 596.655 us; speedup vs baseline: 1.2267x; 1.2267x over previous
//
#include <hip/hip_runtime.h>
#include <hip/hip_bf16.h>

// Swin shifted-window attention, fully fused per-window. FP32 global IO,
// bf16 MFMA internals. B=4, H=W=256, C=192, NH=6, HD=32, WS=8, SHIFT=4, "SW".
// One block = one window (64 tokens).
// R1: 768 threads = 12 waves (was 6). Same LDS (139.5 KB -> 1 block/CU), but
// 12 waves/CU instead of 6: occupancy 17.6% -> ~35%, halved per-wave critical
// path in every phase. Head h is handled by wave pair (2h, 2h+1), split on mt.

typedef __bf16 bf16x8 __attribute__((ext_vector_type(8)));
typedef float  f32x4  __attribute__((ext_vector_type(4)));

static __device__ __forceinline__ unsigned short f2bf(float f) {
    __bf16 h = (__bf16)f;                       // RNE f32->bf16
    return __builtin_bit_cast(unsigned short, h);
}

// ---------------------------------------------------------------------------
// LDS layout (ushort units):
//   QS  [64][200]  @ 0      (q, row=token, col=feat, pad 200)  -- reused as OS
//   KS  [64][200]  @ 12800
//   VT  [192][72]  @ 25600  (v transposed: row=feat, col=token, pad 72)
//   PS  [6][64][72]@ 39424  (per-head P)  -- first 12800 aliased as XS (x tile)
//   RELF[1350] f32 @ 67072  (rel_pos table, 225*6, kept fp32)
// total 69772 ushort = 139544 B  (< 160 KiB gfx950 LDS)

__global__ __launch_bounds__(768)
void wmsa_fused(const float* __restrict__ x,        // [4,256,256,192]
                const float* __restrict__ wq,       // [192][576]
                const float* __restrict__ b_qkv,    // [576]
                const float* __restrict__ wl,       // [192][192]
                const float* __restrict__ b_lin,    // [192]
                const float* __restrict__ rel_pos,  // [225*6]
                float* __restrict__ out)            // [4,256,256,192]
{
    __shared__ __align__(16) unsigned short smem[69772];
    unsigned short* QS  = smem;            // also OS
    unsigned short* KS  = smem + 12800;
    unsigned short* VT  = smem + 25600;
    unsigned short* PS  = smem + 39424;
    unsigned short* XS  = smem + 39424;    // alias over PS (phase 1-2 only)
    float*          RELF = (float*)(smem + 67072);

    const int tid  = threadIdx.x;
    const int lane = tid & 63;
    const int w2   = tid >> 6;     // wave id, 0..11
    const int l15  = lane & 15;
    const int quad = lane >> 4;

    const int bx = blockIdx.x;     // 4096 = 4 * 32 * 32
    const int b  = bx >> 10;
    const int wh = (bx >> 5) & 31;
    const int ww = bx & 31;

    // ---- Phase 1: stage rolled x rows (64 tokens x 192, fp32 -> bf16) + rel_pos
    // shifted image: xs[h][w] = x[(h+4)%256][(w+4)%256]
    for (int i = tid; i < 3072; i += 768) {           // 64 rows * 48 float4 chunks
        int row = i / 48, cc = i % 48;
        int hs = wh * 8 + (row >> 3), wsx = ww * 8 + (row & 7);
        int ho = (hs + 4) & 255,      wo  = (wsx + 4) & 255;
        float4 v = *(const float4*)(x + ((((b << 8) + ho) << 8) + wo) * 192 + cc * 4);
        ushort4 p;
        p.x = f2bf(v.x); p.y = f2bf(v.y); p.z = f2bf(v.z); p.w = f2bf(v.w);
        *(ushort4*)(XS + row * 200 + cc * 4) = p;
    }
    for (int i = tid; i < 1350; i += 768) RELF[i] = rel_pos[i];
    __syncthreads();

    // ---- Phase 2: qkv = xs @ Wqkv + b_qkv  -> QS / KS / VT
    // wave w2 handles ntiles [3*w2, 3*w2+3).  B-frag gathered from global fp32 wq:
    // bfr[j] = (bf16)Wqkv[ks*32 + quad*8 + j][nt*16 + l15]
    #pragma unroll 1
    for (int ntl = 0; ntl < 3; ++ntl) {
        int nt = w2 * 3 + ntl;                         // 0..35
        f32x4 acc[4];
        #pragma unroll
        for (int mt = 0; mt < 4; ++mt) acc[mt] = (f32x4){0.f, 0.f, 0.f, 0.f};
        #pragma unroll
        for (int ks = 0; ks < 6; ++ks) {
            const float* wp = wq + (ks * 32 + quad * 8) * 576 + nt * 16 + l15;
            bf16x8 bfr;
            #pragma unroll
            for (int j = 0; j < 8; ++j) bfr[j] = (__bf16)wp[j * 576];
            #pragma unroll
            for (int mt = 0; mt < 4; ++mt) {
                bf16x8 afr = *(const bf16x8*)(XS + (mt * 16 + l15) * 200 + ks * 32 + quad * 8);
                acc[mt] = __builtin_amdgcn_mfma_f32_16x16x32_bf16(afr, bfr, acc[mt], 0, 0, 0);
            }
        }
        int col  = nt * 16 + l15;                      // global qkv col 0..575
        float bv = b_qkv[col];
        int sidx = col / 192;                          // 0=q 1=k 2=v (uniform per nt)
        int cin  = col % 192;
        #pragma unroll
        for (int mt = 0; mt < 4; ++mt) {
            if (sidx == 2) {                           // V: store transposed, 4 tokens packed
                ushort4 pk;
                pk.x = f2bf(acc[mt][0] + bv);
                pk.y = f2bf(acc[mt][1] + bv);
                pk.z = f2bf(acc[mt][2] + bv);
                pk.w = f2bf(acc[mt][3] + bv);
                *(ushort4*)(VT + cin * 72 + mt * 16 + quad * 4) = pk;
            } else {
                unsigned short* dst = (sidx == 0) ? QS : KS;
                #pragma unroll
                for (int r = 0; r < 4; ++r)
                    dst[(mt * 16 + quad * 4 + r) * 200 + cin] = f2bf(acc[mt][r] + bv);
            }
        }
    }
    __syncthreads();

    // ---- Phase 3a: S = Q Kt * scale + bias, mask, softmax -> PS[w] (wave pair = head)
    const int w  = w2 >> 1;        // head 0..5
    const int mh = (w2 & 1) * 2;   // this wave's mt base: 0 or 2
    {
        const float SCALE = 0.17677669529663687f;      // 32^-0.5
        f32x4 sa[2][4];
        #pragma unroll
        for (int mi = 0; mi < 2; ++mi)
            #pragma unroll
            for (int nt = 0; nt < 4; ++nt) sa[mi][nt] = (f32x4){0.f, 0.f, 0.f, 0.f};
        bf16x8 kf[4];
        #pragma unroll
        for (int nt = 0; nt < 4; ++nt)
            kf[nt] = *(const bf16x8*)(KS + (nt * 16 + l15) * 200 + w * 32 + quad * 8);
        #pragma unroll
        for (int mi = 0; mi < 2; ++mi) {
            int mt = mh + mi;
            bf16x8 afr = *(const bf16x8*)(QS + (mt * 16 + l15) * 200 + w * 32 + quad * 8);
            #pragma unroll
            for (int nt = 0; nt < 4; ++nt)
                sa[mi][nt] = __builtin_amdgcn_mfma_f32_16x16x32_bf16(afr, kf[nt], sa[mi][nt], 0, 0, 0);
        }
        // bias + mask  (C-layout: row = mt*16+quad*4+r, col = nt*16+l15)
        float sv[2][4][4];
        const bool mH = (wh == 31), mW = (ww == 31);
        #pragma unroll
        for (int mi = 0; mi < 2; ++mi)
            #pragma unroll
            for (int nt = 0; nt < 4; ++nt)
                #pragma unroll
                for (int r = 0; r < 4; ++r) {
                    int row = (mh + mi) * 16 + quad * 4 + r;
                    int col = nt * 16 + l15;
                    int r1 = row >> 3, c1 = row & 7, r2 = col >> 3, c2 = col & 7;
                    float v = sa[mi][nt][r] * SCALE
                            + RELF[((r1 - r2 + 7) * 15 + (c1 - c2 + 7)) * 6 + w];
                    if ((mH && ((r1 < 4) != (r2 < 4))) || (mW && ((c1 < 4) != (c2 < 4))))
                        v = -1e30f;
                    sv[mi][nt][r] = v;
                }
        // row softmax: each row lives in 4 regs x 16 lanes of one quad-group
        #pragma unroll
        for (int mi = 0; mi < 2; ++mi)
            #pragma unroll
            for (int r = 0; r < 4; ++r) {
                float m = fmaxf(fmaxf(sv[mi][0][r], sv[mi][1][r]),
                                fmaxf(sv[mi][2][r], sv[mi][3][r]));
                m = fmaxf(m, __shfl_xor(m, 1));
                m = fmaxf(m, __shfl_xor(m, 2));
                m = fmaxf(m, __shfl_xor(m, 4));
                m = fmaxf(m, __shfl_xor(m, 8));
                float s = 0.f;
                #pragma unroll
                for (int nt = 0; nt < 4; ++nt) {
                    float p = __expf(sv[mi][nt][r] - m);
                    sv[mi][nt][r] = p;
                    s += p;
                }
                s += __shfl_xor(s, 1);
                s += __shfl_xor(s, 2);
                s += __shfl_xor(s, 4);
                s += __shfl_xor(s, 8);
                float inv = 1.f / s;
                #pragma unroll
                for (int nt = 0; nt < 4; ++nt) sv[mi][nt][r] *= inv;
            }
        unsigned short* myP = PS + w * 4608;           // 64*72
        #pragma unroll
        for (int mi = 0; mi < 2; ++mi)
            #pragma unroll
            for (int nt = 0; nt < 4; ++nt)
                #pragma unroll
                for (int r = 0; r < 4; ++r)
                    myP[((mh + mi) * 16 + quad * 4 + r) * 72 + nt * 16 + l15] = f2bf(sv[mi][nt][r]);
    }
    __syncthreads();   // all QS/KS reads done before OS (=QS) is overwritten

    // ---- Phase 3b: O = P @ V  -> OS (over QS region)
    {
        f32x4 oa[2][2];
        #pragma unroll
        for (int mi = 0; mi < 2; ++mi) { oa[mi][0] = (f32x4){0.f,0.f,0.f,0.f}; oa[mi][1] = (f32x4){0.f,0.f,0.f,0.f}; }
        unsigned short* myP = PS + w * 4608;
        #pragma unroll
        for (int ks2 = 0; ks2 < 2; ++ks2) {
            bf16x8 vf[2];
            #pragma unroll
            for (int nt2 = 0; nt2 < 2; ++nt2)
                vf[nt2] = *(const bf16x8*)(VT + (w * 32 + nt2 * 16 + l15) * 72 + ks2 * 32 + quad * 8);
            #pragma unroll
            for (int mi = 0; mi < 2; ++mi) {
                bf16x8 pf = *(const bf16x8*)(myP + ((mh + mi) * 16 + l15) * 72 + ks2 * 32 + quad * 8);
                #pragma unroll
                for (int nt2 = 0; nt2 < 2; ++nt2)
                    oa[mi][nt2] = __builtin_amdgcn_mfma_f32_16x16x32_bf16(pf, vf[nt2], oa[mi][nt2], 0, 0, 0);
            }
        }
        unsigned short* OS = QS;
        #pragma unroll
        for (int mi = 0; mi < 2; ++mi)
            #pragma unroll
            for (int nt2 = 0; nt2 < 2; ++nt2)
                #pragma unroll
                for (int r = 0; r < 4; ++r)
                    OS[((mh + mi) * 16 + quad * 4 + r) * 200 + w * 32 + nt2 * 16 + l15] = f2bf(oa[mi][nt2][r]);
    }
    __syncthreads();

    // ---- Phase 4: out = OS @ w_lin + b_lin, inverse roll, fp32 store
    // B-frag gathered from global fp32 wl: bfr[j] = (bf16)Wlin[ks*32+quad*8+j][ntg*16+l15]
    {
        const unsigned short* OS = QS;
        int ntg = w2;                                  // 0..11, one col-tile per wave
        f32x4 acc[4];
        #pragma unroll
        for (int mt = 0; mt < 4; ++mt) acc[mt] = (f32x4){0.f, 0.f, 0.f, 0.f};
        #pragma unroll
        for (int ks = 0; ks < 6; ++ks) {
            const float* wp = wl + (ks * 32 + quad * 8) * 192 + ntg * 16 + l15;
            bf16x8 bfr;
            #pragma unroll
            for (int j = 0; j < 8; ++j) bfr[j] = (__bf16)wp[j * 192];
            #pragma unroll
            for (int mt = 0; mt < 4; ++mt) {
                bf16x8 afr = *(const bf16x8*)(OS + (mt * 16 + l15) * 200 + ks * 32 + quad * 8);
                acc[mt] = __builtin_amdgcn_mfma_f32_16x16x32_bf16(afr, bfr, acc[mt], 0, 0, 0);
            }
        }
        int col  = ntg * 16 + l15;                     // 0..191
        float bv = b_lin[col];
        #pragma unroll
        for (int mt = 0; mt < 4; ++mt)
            #pragma unroll
            for (int r = 0; r < 4; ++r) {
                int row = mt * 16 + quad * 4 + r;
                int hs = wh * 8 + (row >> 3), wsx = ww * 8 + (row & 7);
                int ho = (hs + 4) & 255,      wo  = (wsx + 4) & 255;
                out[((((b << 8) + ho) << 8) + wo) * 192 + col] = acc[mt][r] + bv;
            }
    }
}

// ---------------------------------------------------------------------------
extern "C" void kernel_launch(void* const* d_in, const int* in_sizes, int n_in,
                              void* d_out, int out_size, void* d_ws, size_t ws_size,
                              hipStream_t stream) {
    const float* x  = (const float*)d_in[0];   // [4,256,256,192] fp32
    const float* wq = (const float*)d_in[1];   // [192,576]
    const float* bq = (const float*)d_in[2];   // [576]
    const float* wl = (const float*)d_in[3];   // [192,192]
    const float* bl = (const float*)d_in[4];   // [192]
    const float* rp = (const float*)d_in[5];   // [225,6]
    (void)d_ws; (void)ws_size; (void)in_sizes; (void)n_in;

    wmsa_fused<<<4096, 768, 0, stream>>>(x, wq, bq, wl, bl, rp, (float*)d_out);
}

// Round 2
// 582.112 us; speedup vs baseline: 1.2574x; 1.0250x over previous
//
#include <hip/hip_runtime.h>
#include <hip/hip_bf16.h>

// Swin shifted-window attention, fully fused per-window. FP32 global IO,
// bf16 MFMA internals. B=4, H=W=256, C=192, NH=6, HD=32, WS=8, SHIFT=4, "SW".
// One block = one window (64 tokens), 768 threads = 12 waves.
// R2: LDS 139.5KB -> 79.5KB via region reuse (V over XS, P over QS+KS, O over VT,
// rel_pos f16) => 2 blocks/CU, 24 waves/CU. XOR-granule swizzle keeps the
// reused regions 16B-aligned and bank-conflict-free. __launch_bounds__(768,6)
// caps VGPR so the second block actually fits.

typedef __bf16 bf16x8 __attribute__((ext_vector_type(8)));
typedef float  f32x4  __attribute__((ext_vector_type(4)));

static __device__ __forceinline__ unsigned short f2bf(float f) {
    __bf16 h = (__bf16)f;                       // RNE f32->bf16
    return __builtin_bit_cast(unsigned short, h);
}

// ---------------------------------------------------------------------------
// LDS layout (ushort units), total 39750 us = 79500 B  (2 blocks/CU):
//   A @ 0     (12800): XS 64x200 (phase1-2) -> VT 192x64 swz (2b-3b) -> OS 64x200
//   B @ 12800 (12800): QS 64x200  \ (phase2-3a) -> P: 12 waves x 32x64 swz
//   C @ 25600 (12800): KS 64x200  /              (24576 us, phase 3a-3b)
//   RELH @ 38400 (1350): rel_pos table as f16

__global__ __launch_bounds__(768, 6)
void wmsa_fused(const float* __restrict__ x,        // [4,256,256,192]
                const float* __restrict__ wq,       // [192][576]
                const float* __restrict__ b_qkv,    // [576]
                const float* __restrict__ wl,       // [192][192]
                const float* __restrict__ b_lin,    // [192]
                const float* __restrict__ rel_pos,  // [225*6]
                float* __restrict__ out)            // [4,256,256,192]
{
    __shared__ __align__(16) unsigned short smem[39750];
    unsigned short* REGA = smem;            // XS -> VT(swz) -> OS
    unsigned short* QS   = smem + 12800;
    unsigned short* KS   = smem + 25600;
    _Float16*       RELH = (_Float16*)(smem + 38400);

    const int tid  = threadIdx.x;
    const int lane = tid & 63;
    const int w2   = tid >> 6;     // wave id 0..11
    const int l15  = lane & 15;
    const int quad = lane >> 4;

    const int bx = blockIdx.x;     // 4096 = 4 * 32 * 32
    const int b  = bx >> 10;
    const int wh = (bx >> 5) & 31;
    const int ww = bx & 31;

    // ---- Phase 1: stage rolled x rows (64 tokens x 192, fp32 -> bf16) + rel_pos
    for (int i = tid; i < 3072; i += 768) {           // 64 rows * 48 float4 chunks
        int row = i / 48, cc = i % 48;
        int hs = wh * 8 + (row >> 3), wsx = ww * 8 + (row & 7);
        int ho = (hs + 4) & 255,      wo  = (wsx + 4) & 255;
        float4 v = *(const float4*)(x + ((((b << 8) + ho) << 8) + wo) * 192 + cc * 4);
        ushort4 p;
        p.x = f2bf(v.x); p.y = f2bf(v.y); p.z = f2bf(v.z); p.w = f2bf(v.w);
        *(ushort4*)(REGA + row * 200 + cc * 4) = p;
    }
    for (int i = tid; i < 1350; i += 768) RELH[i] = (_Float16)rel_pos[i];
    __syncthreads();                                  // bar1: XS+RELH staged

    // ---- Phase 2: qkv = xs @ Wqkv + b_qkv. Wave w2 owns 16 cols of each of Q/K/V.
    // B-frag gathered from global fp32 wq: bfr[j] = (bf16)Wqkv[ks*32+quad*8+j][col]
    const int colL = w2 * 16 + l15;                   // 0..191
    f32x4 accV[4];
    {
        f32x4 acc[4];
        // ---- Q tile -> QS
        #pragma unroll
        for (int mt = 0; mt < 4; ++mt) acc[mt] = (f32x4){0.f, 0.f, 0.f, 0.f};
        #pragma unroll
        for (int ks = 0; ks < 6; ++ks) {
            const float* wp = wq + (ks * 32 + quad * 8) * 576 + colL;
            bf16x8 bfr;
            #pragma unroll
            for (int j = 0; j < 8; ++j) bfr[j] = (__bf16)wp[j * 576];
            #pragma unroll
            for (int mt = 0; mt < 4; ++mt) {
                bf16x8 afr = *(const bf16x8*)(REGA + (mt * 16 + l15) * 200 + ks * 32 + quad * 8);
                acc[mt] = __builtin_amdgcn_mfma_f32_16x16x32_bf16(afr, bfr, acc[mt], 0, 0, 0);
            }
        }
        {
            float bv = b_qkv[colL];
            #pragma unroll
            for (int mt = 0; mt < 4; ++mt)
                #pragma unroll
                for (int r = 0; r < 4; ++r)
                    QS[(mt * 16 + quad * 4 + r) * 200 + colL] = f2bf(acc[mt][r] + bv);
        }
        // ---- K tile -> KS
        #pragma unroll
        for (int mt = 0; mt < 4; ++mt) acc[mt] = (f32x4){0.f, 0.f, 0.f, 0.f};
        #pragma unroll
        for (int ks = 0; ks < 6; ++ks) {
            const float* wp = wq + (ks * 32 + quad * 8) * 576 + 192 + colL;
            bf16x8 bfr;
            #pragma unroll
            for (int j = 0; j < 8; ++j) bfr[j] = (__bf16)wp[j * 576];
            #pragma unroll
            for (int mt = 0; mt < 4; ++mt) {
                bf16x8 afr = *(const bf16x8*)(REGA + (mt * 16 + l15) * 200 + ks * 32 + quad * 8);
                acc[mt] = __builtin_amdgcn_mfma_f32_16x16x32_bf16(afr, bfr, acc[mt], 0, 0, 0);
            }
        }
        {
            float bv = b_qkv[192 + colL];
            #pragma unroll
            for (int mt = 0; mt < 4; ++mt)
                #pragma unroll
                for (int r = 0; r < 4; ++r)
                    KS[(mt * 16 + quad * 4 + r) * 200 + colL] = f2bf(acc[mt][r] + bv);
        }
        // ---- V tile -> registers (XS still live)
        #pragma unroll
        for (int mt = 0; mt < 4; ++mt) accV[mt] = (f32x4){0.f, 0.f, 0.f, 0.f};
        #pragma unroll
        for (int ks = 0; ks < 6; ++ks) {
            const float* wp = wq + (ks * 32 + quad * 8) * 576 + 384 + colL;
            bf16x8 bfr;
            #pragma unroll
            for (int j = 0; j < 8; ++j) bfr[j] = (__bf16)wp[j * 576];
            #pragma unroll
            for (int mt = 0; mt < 4; ++mt) {
                bf16x8 afr = *(const bf16x8*)(REGA + (mt * 16 + l15) * 200 + ks * 32 + quad * 8);
                accV[mt] = __builtin_amdgcn_mfma_f32_16x16x32_bf16(afr, bfr, accV[mt], 0, 0, 0);
            }
        }
    }
    __syncthreads();                                  // bar2: all XS reads done
    // ---- V store transposed over XS: VT[feat][token], stride 64, XOR swizzle.
    // granule(16B = 8 tokens') index ^= feat&7 keeps 16B alignment, kills conflicts.
    {
        float bv = b_qkv[384 + colL];
        #pragma unroll
        for (int mt = 0; mt < 4; ++mt) {
            ushort4 pk;
            pk.x = f2bf(accV[mt][0] + bv);
            pk.y = f2bf(accV[mt][1] + bv);
            pk.z = f2bf(accV[mt][2] + bv);
            pk.w = f2bf(accV[mt][3] + bv);
            int t0 = mt * 16 + quad * 4;
            int g  = (t0 >> 3) ^ (colL & 7);
            *(ushort4*)(REGA + colL * 64 + g * 8 + (t0 & 7)) = pk;
        }
    }
    __syncthreads();                                  // bar3: Q,K,V visible

    // ---- Phase 3a: S = Q Kt * scale + bias, mask, softmax. Wave pair = head.
    const int w  = w2 >> 1;        // head 0..5
    const int mh = (w2 & 1) * 2;   // mt base: 0 or 2 (rows 0..31 / 32..63)
    unsigned short* myP = QS + w2 * 2048;             // P over B+C, 32x64 swz per wave
    float sv[2][4][4];
    {
        const float SCALE = 0.17677669529663687f;     // 32^-0.5
        f32x4 sa[2][4];
        #pragma unroll
        for (int mi = 0; mi < 2; ++mi)
            #pragma unroll
            for (int nt = 0; nt < 4; ++nt) sa[mi][nt] = (f32x4){0.f, 0.f, 0.f, 0.f};
        bf16x8 kf[4];
        #pragma unroll
        for (int nt = 0; nt < 4; ++nt)
            kf[nt] = *(const bf16x8*)(KS + (nt * 16 + l15) * 200 + w * 32 + quad * 8);
        #pragma unroll
        for (int mi = 0; mi < 2; ++mi) {
            bf16x8 afr = *(const bf16x8*)(QS + ((mh + mi) * 16 + l15) * 200 + w * 32 + quad * 8);
            #pragma unroll
            for (int nt = 0; nt < 4; ++nt)
                sa[mi][nt] = __builtin_amdgcn_mfma_f32_16x16x32_bf16(afr, kf[nt], sa[mi][nt], 0, 0, 0);
        }
        __syncthreads();                              // bar4: all QS/KS reads done
        // bias + mask  (C-layout: row = (mh+mi)*16+quad*4+r, col = nt*16+l15)
        const bool mH = (wh == 31), mW = (ww == 31);
        #pragma unroll
        for (int mi = 0; mi < 2; ++mi)
            #pragma unroll
            for (int nt = 0; nt < 4; ++nt)
                #pragma unroll
                for (int r = 0; r < 4; ++r) {
                    int row = (mh + mi) * 16 + quad * 4 + r;
                    int col = nt * 16 + l15;
                    int r1 = row >> 3, c1 = row & 7, r2 = col >> 3, c2 = col & 7;
                    float v = sa[mi][nt][r] * SCALE
                            + (float)RELH[((r1 - r2 + 7) * 15 + (c1 - c2 + 7)) * 6 + w];
                    if ((mH && ((r1 < 4) != (r2 < 4))) || (mW && ((c1 < 4) != (c2 < 4))))
                        v = -1e30f;
                    sv[mi][nt][r] = v;
                }
        // row softmax: each row lives in 4 regs x 16 lanes of one quad-group
        #pragma unroll
        for (int mi = 0; mi < 2; ++mi)
            #pragma unroll
            for (int r = 0; r < 4; ++r) {
                float m = fmaxf(fmaxf(sv[mi][0][r], sv[mi][1][r]),
                                fmaxf(sv[mi][2][r], sv[mi][3][r]));
                m = fmaxf(m, __shfl_xor(m, 1));
                m = fmaxf(m, __shfl_xor(m, 2));
                m = fmaxf(m, __shfl_xor(m, 4));
                m = fmaxf(m, __shfl_xor(m, 8));
                float s = 0.f;
                #pragma unroll
                for (int nt = 0; nt < 4; ++nt) {
                    float p = __expf(sv[mi][nt][r] - m);
                    sv[mi][nt][r] = p;
                    s += p;
                }
                s += __shfl_xor(s, 1);
                s += __shfl_xor(s, 2);
                s += __shfl_xor(s, 4);
                s += __shfl_xor(s, 8);
                float inv = 1.f / s;
                #pragma unroll
                for (int nt = 0; nt < 4; ++nt) sv[mi][nt][r] *= inv;
            }
        // P write (own region, swizzled; writer == reader, no barrier needed)
        #pragma unroll
        for (int mi = 0; mi < 2; ++mi)
            #pragma unroll
            for (int nt = 0; nt < 4; ++nt)
                #pragma unroll
                for (int r = 0; r < 4; ++r) {
                    int row = mi * 16 + quad * 4 + r;          // local 0..31
                    int col = nt * 16 + l15;                   // 0..63
                    myP[row * 64 + (((col >> 3) ^ (row & 7)) << 3) + (col & 7)]
                        = f2bf(sv[mi][nt][r]);
                }
    }

    // ---- Phase 3b: O = P @ V
    {
        f32x4 oa[2][2];
        #pragma unroll
        for (int mi = 0; mi < 2; ++mi) {
            oa[mi][0] = (f32x4){0.f,0.f,0.f,0.f};
            oa[mi][1] = (f32x4){0.f,0.f,0.f,0.f};
        }
        #pragma unroll
        for (int ks2 = 0; ks2 < 2; ++ks2) {
            bf16x8 vf[2];
            #pragma unroll
            for (int nt2 = 0; nt2 < 2; ++nt2) {
                int fr = w * 32 + nt2 * 16 + l15;              // feature row of VT
                int g  = (ks2 * 4 + quad) ^ (fr & 7);
                vf[nt2] = *(const bf16x8*)(REGA + fr * 64 + g * 8);
            }
            #pragma unroll
            for (int mi = 0; mi < 2; ++mi) {
                int row2 = mi * 16 + l15;                      // local P row
                int g2   = (ks2 * 4 + quad) ^ (row2 & 7);
                bf16x8 pf = *(const bf16x8*)(myP + row2 * 64 + g2 * 8);
                #pragma unroll
                for (int nt2 = 0; nt2 < 2; ++nt2)
                    oa[mi][nt2] = __builtin_amdgcn_mfma_f32_16x16x32_bf16(pf, vf[nt2], oa[mi][nt2], 0, 0, 0);
            }
        }
        __syncthreads();                              // bar5: all VT reads done
        unsigned short* OS = REGA;                    // O over VT region, 64x200
        #pragma unroll
        for (int mi = 0; mi < 2; ++mi)
            #pragma unroll
            for (int nt2 = 0; nt2 < 2; ++nt2)
                #pragma unroll
                for (int r = 0; r < 4; ++r)
                    OS[((mh + mi) * 16 + quad * 4 + r) * 200 + w * 32 + nt2 * 16 + l15]
                        = f2bf(oa[mi][nt2][r]);
    }
    __syncthreads();                                  // bar6: O visible

    // ---- Phase 4: out = OS @ w_lin + b_lin, inverse roll, fp32 store
    {
        const unsigned short* OS = REGA;
        int ntg = w2;                                  // 0..11, one col-tile per wave
        f32x4 acc[4];
        #pragma unroll
        for (int mt = 0; mt < 4; ++mt) acc[mt] = (f32x4){0.f, 0.f, 0.f, 0.f};
        #pragma unroll
        for (int ks = 0; ks < 6; ++ks) {
            const float* wp = wl + (ks * 32 + quad * 8) * 192 + ntg * 16 + l15;
            bf16x8 bfr;
            #pragma unroll
            for (int j = 0; j < 8; ++j) bfr[j] = (__bf16)wp[j * 192];
            #pragma unroll
            for (int mt = 0; mt < 4; ++mt) {
                bf16x8 afr = *(const bf16x8*)(OS + (mt * 16 + l15) * 200 + ks * 32 + quad * 8);
                acc[mt] = __builtin_amdgcn_mfma_f32_16x16x32_bf16(afr, bfr, acc[mt], 0, 0, 0);
            }
        }
        int col  = ntg * 16 + l15;                     // 0..191
        float bv = b_lin[col];
        #pragma unroll
        for (int mt = 0; mt < 4; ++mt)
            #pragma unroll
            for (int r = 0; r < 4; ++r) {
                int row = mt * 16 + quad * 4 + r;
                int hs = wh * 8 + (row >> 3), wsx = ww * 8 + (row & 7);
                int ho = (hs + 4) & 255,      wo  = (wsx + 4) & 255;
                out[((((b << 8) + ho) << 8) + wo) * 192 + col] = acc[mt][r] + bv;
            }
    }
}

// ---------------------------------------------------------------------------
extern "C" void kernel_launch(void* const* d_in, const int* in_sizes, int n_in,
                              void* d_out, int out_size, void* d_ws, size_t ws_size,
                              hipStream_t stream) {
    const float* x  = (const float*)d_in[0];   // [4,256,256,192] fp32
    const float* wq = (const float*)d_in[1];   // [192,576]
    const float* bq = (const float*)d_in[2];   // [576]
    const float* wl = (const float*)d_in[3];   // [192,192]
    const float* bl = (const float*)d_in[4];   // [192]
    const float* rp = (const float*)d_in[5];   // [225,6]
    (void)d_ws; (void)ws_size; (void)in_sizes; (void)n_in;

    wmsa_fused<<<4096, 768, 0, stream>>>(x, wq, bq, wl, bl, rp, (float*)d_out);
}

// Round 3
// 566.894 us; speedup vs baseline: 1.2911x; 1.0268x over previous
//
#include <hip/hip_runtime.h>
#include <hip/hip_bf16.h>

// Swin shifted-window attention, fully fused per-window. FP32 global IO,
// bf16 MFMA internals. B=4, H=W=256, C=192, NH=6, HD=32, WS=8, SHIFT=4, "SW".
// One block = one window (64 tokens), 768 threads = 12 waves.
// R2: LDS 139.5KB -> 79.5KB via region reuse => 2 blocks/CU, 24 waves/CU.
// R3: drop the launch_bounds min-waves arg. (768,6) clamped VGPR to 40 and the
// compiler spilled ~520MB/dispatch to scratch (FETCH 108->289MB, WRITE
// 196->540MB). Plain (768) gives ~68 VGPR -> 7 waves/SIMD possible, LDS still
// the binding limit at 2 blocks/CU, no spills.

typedef __bf16 bf16x8 __attribute__((ext_vector_type(8)));
typedef float  f32x4  __attribute__((ext_vector_type(4)));

static __device__ __forceinline__ unsigned short f2bf(float f) {
    __bf16 h = (__bf16)f;                       // RNE f32->bf16
    return __builtin_bit_cast(unsigned short, h);
}

// ---------------------------------------------------------------------------
// LDS layout (ushort units), total 39750 us = 79500 B  (2 blocks/CU):
//   A @ 0     (12800): XS 64x200 (phase1-2) -> VT 192x64 swz (2b-3b) -> OS 64x200
//   B @ 12800 (12800): QS 64x200  \ (phase2-3a) -> P: 12 waves x 32x64 swz
//   C @ 25600 (12800): KS 64x200  /              (24576 us, phase 3a-3b)
//   RELH @ 38400 (1350): rel_pos table as f16

__global__ __launch_bounds__(768)
void wmsa_fused(const float* __restrict__ x,        // [4,256,256,192]
                const float* __restrict__ wq,       // [192][576]
                const float* __restrict__ b_qkv,    // [576]
                const float* __restrict__ wl,       // [192][192]
                const float* __restrict__ b_lin,    // [192]
                const float* __restrict__ rel_pos,  // [225*6]
                float* __restrict__ out)            // [4,256,256,192]
{
    __shared__ __align__(16) unsigned short smem[39750];
    unsigned short* REGA = smem;            // XS -> VT(swz) -> OS
    unsigned short* QS   = smem + 12800;
    unsigned short* KS   = smem + 25600;
    _Float16*       RELH = (_Float16*)(smem + 38400);

    const int tid  = threadIdx.x;
    const int lane = tid & 63;
    const int w2   = tid >> 6;     // wave id 0..11
    const int l15  = lane & 15;
    const int quad = lane >> 4;

    const int bx = blockIdx.x;     // 4096 = 4 * 32 * 32
    const int b  = bx >> 10;
    const int wh = (bx >> 5) & 31;
    const int ww = bx & 31;

    // ---- Phase 1: stage rolled x rows (64 tokens x 192, fp32 -> bf16) + rel_pos
    for (int i = tid; i < 3072; i += 768) {           // 64 rows * 48 float4 chunks
        int row = i / 48, cc = i % 48;
        int hs = wh * 8 + (row >> 3), wsx = ww * 8 + (row & 7);
        int ho = (hs + 4) & 255,      wo  = (wsx + 4) & 255;
        float4 v = *(const float4*)(x + ((((b << 8) + ho) << 8) + wo) * 192 + cc * 4);
        ushort4 p;
        p.x = f2bf(v.x); p.y = f2bf(v.y); p.z = f2bf(v.z); p.w = f2bf(v.w);
        *(ushort4*)(REGA + row * 200 + cc * 4) = p;
    }
    for (int i = tid; i < 1350; i += 768) RELH[i] = (_Float16)rel_pos[i];
    __syncthreads();                                  // bar1: XS+RELH staged

    // ---- Phase 2: qkv = xs @ Wqkv + b_qkv. Wave w2 owns 16 cols of each of Q/K/V.
    // B-frag gathered from global fp32 wq: bfr[j] = (bf16)Wqkv[ks*32+quad*8+j][col]
    const int colL = w2 * 16 + l15;                   // 0..191
    f32x4 accV[4];
    {
        f32x4 acc[4];
        // ---- Q tile -> QS
        #pragma unroll
        for (int mt = 0; mt < 4; ++mt) acc[mt] = (f32x4){0.f, 0.f, 0.f, 0.f};
        #pragma unroll
        for (int ks = 0; ks < 6; ++ks) {
            const float* wp = wq + (ks * 32 + quad * 8) * 576 + colL;
            bf16x8 bfr;
            #pragma unroll
            for (int j = 0; j < 8; ++j) bfr[j] = (__bf16)wp[j * 576];
            #pragma unroll
            for (int mt = 0; mt < 4; ++mt) {
                bf16x8 afr = *(const bf16x8*)(REGA + (mt * 16 + l15) * 200 + ks * 32 + quad * 8);
                acc[mt] = __builtin_amdgcn_mfma_f32_16x16x32_bf16(afr, bfr, acc[mt], 0, 0, 0);
            }
        }
        {
            float bv = b_qkv[colL];
            #pragma unroll
            for (int mt = 0; mt < 4; ++mt)
                #pragma unroll
                for (int r = 0; r < 4; ++r)
                    QS[(mt * 16 + quad * 4 + r) * 200 + colL] = f2bf(acc[mt][r] + bv);
        }
        // ---- K tile -> KS
        #pragma unroll
        for (int mt = 0; mt < 4; ++mt) acc[mt] = (f32x4){0.f, 0.f, 0.f, 0.f};
        #pragma unroll
        for (int ks = 0; ks < 6; ++ks) {
            const float* wp = wq + (ks * 32 + quad * 8) * 576 + 192 + colL;
            bf16x8 bfr;
            #pragma unroll
            for (int j = 0; j < 8; ++j) bfr[j] = (__bf16)wp[j * 576];
            #pragma unroll
            for (int mt = 0; mt < 4; ++mt) {
                bf16x8 afr = *(const bf16x8*)(REGA + (mt * 16 + l15) * 200 + ks * 32 + quad * 8);
                acc[mt] = __builtin_amdgcn_mfma_f32_16x16x32_bf16(afr, bfr, acc[mt], 0, 0, 0);
            }
        }
        {
            float bv = b_qkv[192 + colL];
            #pragma unroll
            for (int mt = 0; mt < 4; ++mt)
                #pragma unroll
                for (int r = 0; r < 4; ++r)
                    KS[(mt * 16 + quad * 4 + r) * 200 + colL] = f2bf(acc[mt][r] + bv);
        }
        // ---- V tile -> registers (XS still live)
        #pragma unroll
        for (int mt = 0; mt < 4; ++mt) accV[mt] = (f32x4){0.f, 0.f, 0.f, 0.f};
        #pragma unroll
        for (int ks = 0; ks < 6; ++ks) {
            const float* wp = wq + (ks * 32 + quad * 8) * 576 + 384 + colL;
            bf16x8 bfr;
            #pragma unroll
            for (int j = 0; j < 8; ++j) bfr[j] = (__bf16)wp[j * 576];
            #pragma unroll
            for (int mt = 0; mt < 4; ++mt) {
                bf16x8 afr = *(const bf16x8*)(REGA + (mt * 16 + l15) * 200 + ks * 32 + quad * 8);
                accV[mt] = __builtin_amdgcn_mfma_f32_16x16x32_bf16(afr, bfr, accV[mt], 0, 0, 0);
            }
        }
    }
    __syncthreads();                                  // bar2: all XS reads done
    // ---- V store transposed over XS: VT[feat][token], stride 64, XOR swizzle.
    // granule(16B = 8 tokens') index ^= feat&7 keeps 16B alignment, kills conflicts.
    {
        float bv = b_qkv[384 + colL];
        #pragma unroll
        for (int mt = 0; mt < 4; ++mt) {
            ushort4 pk;
            pk.x = f2bf(accV[mt][0] + bv);
            pk.y = f2bf(accV[mt][1] + bv);
            pk.z = f2bf(accV[mt][2] + bv);
            pk.w = f2bf(accV[mt][3] + bv);
            int t0 = mt * 16 + quad * 4;
            int g  = (t0 >> 3) ^ (colL & 7);
            *(ushort4*)(REGA + colL * 64 + g * 8 + (t0 & 7)) = pk;
        }
    }
    __syncthreads();                                  // bar3: Q,K,V visible

    // ---- Phase 3a: S = Q Kt * scale + bias, mask, softmax. Wave pair = head.
    const int w  = w2 >> 1;        // head 0..5
    const int mh = (w2 & 1) * 2;   // mt base: 0 or 2 (rows 0..31 / 32..63)
    unsigned short* myP = QS + w2 * 2048;             // P over B+C, 32x64 swz per wave
    float sv[2][4][4];
    {
        const float SCALE = 0.17677669529663687f;     // 32^-0.5
        f32x4 sa[2][4];
        #pragma unroll
        for (int mi = 0; mi < 2; ++mi)
            #pragma unroll
            for (int nt = 0; nt < 4; ++nt) sa[mi][nt] = (f32x4){0.f, 0.f, 0.f, 0.f};
        bf16x8 kf[4];
        #pragma unroll
        for (int nt = 0; nt < 4; ++nt)
            kf[nt] = *(const bf16x8*)(KS + (nt * 16 + l15) * 200 + w * 32 + quad * 8);
        #pragma unroll
        for (int mi = 0; mi < 2; ++mi) {
            bf16x8 afr = *(const bf16x8*)(QS + ((mh + mi) * 16 + l15) * 200 + w * 32 + quad * 8);
            #pragma unroll
            for (int nt = 0; nt < 4; ++nt)
                sa[mi][nt] = __builtin_amdgcn_mfma_f32_16x16x32_bf16(afr, kf[nt], sa[mi][nt], 0, 0, 0);
        }
        __syncthreads();                              // bar4: all QS/KS reads done
        // bias + mask  (C-layout: row = (mh+mi)*16+quad*4+r, col = nt*16+l15)
        const bool mH = (wh == 31), mW = (ww == 31);
        #pragma unroll
        for (int mi = 0; mi < 2; ++mi)
            #pragma unroll
            for (int nt = 0; nt < 4; ++nt)
                #pragma unroll
                for (int r = 0; r < 4; ++r) {
                    int row = (mh + mi) * 16 + quad * 4 + r;
                    int col = nt * 16 + l15;
                    int r1 = row >> 3, c1 = row & 7, r2 = col >> 3, c2 = col & 7;
                    float v = sa[mi][nt][r] * SCALE
                            + (float)RELH[((r1 - r2 + 7) * 15 + (c1 - c2 + 7)) * 6 + w];
                    if ((mH && ((r1 < 4) != (r2 < 4))) || (mW && ((c1 < 4) != (c2 < 4))))
                        v = -1e30f;
                    sv[mi][nt][r] = v;
                }
        // row softmax: each row lives in 4 regs x 16 lanes of one quad-group
        #pragma unroll
        for (int mi = 0; mi < 2; ++mi)
            #pragma unroll
            for (int r = 0; r < 4; ++r) {
                float m = fmaxf(fmaxf(sv[mi][0][r], sv[mi][1][r]),
                                fmaxf(sv[mi][2][r], sv[mi][3][r]));
                m = fmaxf(m, __shfl_xor(m, 1));
                m = fmaxf(m, __shfl_xor(m, 2));
                m = fmaxf(m, __shfl_xor(m, 4));
                m = fmaxf(m, __shfl_xor(m, 8));
                float s = 0.f;
                #pragma unroll
                for (int nt = 0; nt < 4; ++nt) {
                    float p = __expf(sv[mi][nt][r] - m);
                    sv[mi][nt][r] = p;
                    s += p;
                }
                s += __shfl_xor(s, 1);
                s += __shfl_xor(s, 2);
                s += __shfl_xor(s, 4);
                s += __shfl_xor(s, 8);
                float inv = 1.f / s;
                #pragma unroll
                for (int nt = 0; nt < 4; ++nt) sv[mi][nt][r] *= inv;
            }
        // P write (own region, swizzled; writer == reader, no barrier needed)
        #pragma unroll
        for (int mi = 0; mi < 2; ++mi)
            #pragma unroll
            for (int nt = 0; nt < 4; ++nt)
                #pragma unroll
                for (int r = 0; r < 4; ++r) {
                    int row = mi * 16 + quad * 4 + r;          // local 0..31
                    int col = nt * 16 + l15;                   // 0..63
                    myP[row * 64 + (((col >> 3) ^ (row & 7)) << 3) + (col & 7)]
                        = f2bf(sv[mi][nt][r]);
                }
    }

    // ---- Phase 3b: O = P @ V
    {
        f32x4 oa[2][2];
        #pragma unroll
        for (int mi = 0; mi < 2; ++mi) {
            oa[mi][0] = (f32x4){0.f,0.f,0.f,0.f};
            oa[mi][1] = (f32x4){0.f,0.f,0.f,0.f};
        }
        #pragma unroll
        for (int ks2 = 0; ks2 < 2; ++ks2) {
            bf16x8 vf[2];
            #pragma unroll
            for (int nt2 = 0; nt2 < 2; ++nt2) {
                int fr = w * 32 + nt2 * 16 + l15;              // feature row of VT
                int g  = (ks2 * 4 + quad) ^ (fr & 7);
                vf[nt2] = *(const bf16x8*)(REGA + fr * 64 + g * 8);
            }
            #pragma unroll
            for (int mi = 0; mi < 2; ++mi) {
                int row2 = mi * 16 + l15;                      // local P row
                int g2   = (ks2 * 4 + quad) ^ (row2 & 7);
                bf16x8 pf = *(const bf16x8*)(myP + row2 * 64 + g2 * 8);
                #pragma unroll
                for (int nt2 = 0; nt2 < 2; ++nt2)
                    oa[mi][nt2] = __builtin_amdgcn_mfma_f32_16x16x32_bf16(pf, vf[nt2], oa[mi][nt2], 0, 0, 0);
            }
        }
        __syncthreads();                              // bar5: all VT reads done
        unsigned short* OS = REGA;                    // O over VT region, 64x200
        #pragma unroll
        for (int mi = 0; mi < 2; ++mi)
            #pragma unroll
            for (int nt2 = 0; nt2 < 2; ++nt2)
                #pragma unroll
                for (int r = 0; r < 4; ++r)
                    OS[((mh + mi) * 16 + quad * 4 + r) * 200 + w * 32 + nt2 * 16 + l15]
                        = f2bf(oa[mi][nt2][r]);
    }
    __syncthreads();                                  // bar6: O visible

    // ---- Phase 4: out = OS @ w_lin + b_lin, inverse roll, fp32 store
    {
        const unsigned short* OS = REGA;
        int ntg = w2;                                  // 0..11, one col-tile per wave
        f32x4 acc[4];
        #pragma unroll
        for (int mt = 0; mt < 4; ++mt) acc[mt] = (f32x4){0.f, 0.f, 0.f, 0.f};
        #pragma unroll
        for (int ks = 0; ks < 6; ++ks) {
            const float* wp = wl + (ks * 32 + quad * 8) * 192 + ntg * 16 + l15;
            bf16x8 bfr;
            #pragma unroll
            for (int j = 0; j < 8; ++j) bfr[j] = (__bf16)wp[j * 192];
            #pragma unroll
            for (int mt = 0; mt < 4; ++mt) {
                bf16x8 afr = *(const bf16x8*)(OS + (mt * 16 + l15) * 200 + ks * 32 + quad * 8);
                acc[mt] = __builtin_amdgcn_mfma_f32_16x16x32_bf16(afr, bfr, acc[mt], 0, 0, 0);
            }
        }
        int col  = ntg * 16 + l15;                     // 0..191
        float bv = b_lin[col];
        #pragma unroll
        for (int mt = 0; mt < 4; ++mt)
            #pragma unroll
            for (int r = 0; r < 4; ++r) {
                int row = mt * 16 + quad * 4 + r;
                int hs = wh * 8 + (row >> 3), wsx = ww * 8 + (row & 7);
                int ho = (hs + 4) & 255,      wo  = (wsx + 4) & 255;
                out[((((b << 8) + ho) << 8) + wo) * 192 + col] = acc[mt][r] + bv;
            }
    }
}

// ---------------------------------------------------------------------------
extern "C" void kernel_launch(void* const* d_in, const int* in_sizes, int n_in,
                              void* d_out, int out_size, void* d_ws, size_t ws_size,
                              hipStream_t stream) {
    const float* x  = (const float*)d_in[0];   // [4,256,256,192] fp32
    const float* wq = (const float*)d_in[1];   // [192,576]
    const float* bq = (const float*)d_in[2];   // [576]
    const float* wl = (const float*)d_in[3];   // [192,192]
    const float* bl = (const float*)d_in[4];   // [192]
    const float* rp = (const float*)d_in[5];   // [225,6]
    (void)d_ws; (void)ws_size; (void)in_sizes; (void)n_in;

    wmsa_fused<<<4096, 768, 0, stream>>>(x, wq, bq, wl, bl, rp, (float*)d_out);
}

// Round 4
// 436.672 us; speedup vs baseline: 1.6762x; 1.2982x over previous
//
#include <hip/hip_runtime.h>
#include <hip/hip_bf16.h>

// Swin shifted-window attention, fully fused per-window. FP32 global IO,
// bf16 MFMA internals. B=4, H=W=256, C=192, NH=6, HD=32, WS=8, SHIFT=4, "SW".
// One block = one window (64 tokens), 768 threads = 12 waves.
// R2: LDS 139.5KB -> 79.5KB via region reuse.
// R3: no launch_bounds min-waves clamp (spills). Occupancy parked at ~12
//     waves/CU (unified VGPR+AGPR total ~128/wave -> 16-wave capacity, one
//     12-wave block resident).
// R4: pre-pack wq/wl to bf16 in MFMA-fragment order into d_ws via a prep
//     kernel. B-fragments become ONE coalesced global_load_dwordx4 instead of
//     8 strided dword loads + 8 cvts (~192 strided loads + ~1500 VALU ops per
//     wave removed from the inter-barrier critical path).

typedef __bf16 bf16x8 __attribute__((ext_vector_type(8)));
typedef float  f32x4  __attribute__((ext_vector_type(4)));

static __device__ __forceinline__ unsigned short f2bf(float f) {
    __bf16 h = (__bf16)f;                       // RNE f32->bf16
    return __builtin_bit_cast(unsigned short, h);
}

// ---------------------------------------------------------------------------
// Weight pre-pack: wp[((nt*6+ks)*64+lane)*8 + j] = (bf16)W[ks*32+(lane>>4)*8+j][col(nt,lane)]
//   wq: nt = s*12 + w2 (s=0 Q, 1 K, 2 V), col = s*192 + w2*16 + (lane&15)   -> 110592 elems
//   wl: nt = ntg (0..11),                col = ntg*16 + (lane&15)           -> +36864 elems
// total 147456 bf16 = 294912 B in d_ws.

__global__ __launch_bounds__(256)
void pack_w(const float* __restrict__ wq, const float* __restrict__ wl,
            unsigned short* __restrict__ wp)
{
    int e = blockIdx.x * 256 + threadIdx.x;           // 0..147455
    if (e < 110592) {
        int j = e & 7, lane = (e >> 3) & 63, f = e >> 9;   // f = nt*6+ks
        int ks = f % 6, nt = f / 6;
        int s = nt / 12, wi = nt % 12;
        int row = ks * 32 + (lane >> 4) * 8 + j;
        int col = s * 192 + wi * 16 + (lane & 15);
        wp[e] = f2bf(wq[row * 576 + col]);
    } else {
        int e2 = e - 110592;
        int j = e2 & 7, lane = (e2 >> 3) & 63, f = e2 >> 9; // f = ntg*6+ks
        int ks = f % 6, ntg = f / 6;
        int row = ks * 32 + (lane >> 4) * 8 + j;
        int col = ntg * 16 + (lane & 15);
        wp[e] = f2bf(wl[row * 192 + col]);
    }
}

// ---------------------------------------------------------------------------
// LDS layout (ushort units), total 39750 us = 79500 B:
//   A @ 0     (12800): XS 64x200 (phase1-2) -> VT 192x64 swz (2b-3b) -> OS 64x200
//   B @ 12800 (12800): QS 64x200  \ (phase2-3a) -> P: 12 waves x 32x64 swz
//   C @ 25600 (12800): KS 64x200  /              (24576 us, phase 3a-3b)
//   RELH @ 38400 (1350): rel_pos table as f16

template<bool PACKED>
__global__ __launch_bounds__(768)
void wmsa_fused(const float* __restrict__ x,        // [4,256,256,192]
                const float* __restrict__ wq,       // [192][576]
                const float* __restrict__ b_qkv,    // [576]
                const float* __restrict__ wl,       // [192][192]
                const float* __restrict__ b_lin,    // [192]
                const float* __restrict__ rel_pos,  // [225*6]
                const unsigned short* __restrict__ wp,  // packed weights (or null)
                float* __restrict__ out)            // [4,256,256,192]
{
    __shared__ __align__(16) unsigned short smem[39750];
    unsigned short* REGA = smem;            // XS -> VT(swz) -> OS
    unsigned short* QS   = smem + 12800;
    unsigned short* KS   = smem + 25600;
    _Float16*       RELH = (_Float16*)(smem + 38400);

    const int tid  = threadIdx.x;
    const int lane = tid & 63;
    const int w2   = tid >> 6;     // wave id 0..11
    const int l15  = lane & 15;
    const int quad = lane >> 4;

    const int bx = blockIdx.x;     // 4096 = 4 * 32 * 32
    const int b  = bx >> 10;
    const int wh = (bx >> 5) & 31;
    const int ww = bx & 31;

    // ---- Phase 1: stage rolled x rows (64 tokens x 192, fp32 -> bf16) + rel_pos
    for (int i = tid; i < 3072; i += 768) {           // 64 rows * 48 float4 chunks
        int row = i / 48, cc = i % 48;
        int hs = wh * 8 + (row >> 3), wsx = ww * 8 + (row & 7);
        int ho = (hs + 4) & 255,      wo  = (wsx + 4) & 255;
        float4 v = *(const float4*)(x + ((((b << 8) + ho) << 8) + wo) * 192 + cc * 4);
        ushort4 p;
        p.x = f2bf(v.x); p.y = f2bf(v.y); p.z = f2bf(v.z); p.w = f2bf(v.w);
        *(ushort4*)(REGA + row * 200 + cc * 4) = p;
    }
    for (int i = tid; i < 1350; i += 768) RELH[i] = (_Float16)rel_pos[i];
    __syncthreads();                                  // bar1: XS+RELH staged

    // ---- Phase 2: qkv = xs @ Wqkv + b_qkv. Wave w2 owns 16 cols of each of Q/K/V.
    const int colL = w2 * 16 + l15;                   // 0..191
    // packed fragment bases: sector s at wp + ((s*12+w2)*6*64 + lane*? ...)
    const unsigned short* fqQ = wp + (w2 * 6) * 512 + lane * 8;          // s=0
    const unsigned short* fqK = fqQ + 12 * 6 * 512;                      // s=1
    const unsigned short* fqV = fqQ + 24 * 6 * 512;                      // s=2
    f32x4 accV[4];
    {
        f32x4 acc[4];
        // ---- Q tile -> QS
        #pragma unroll
        for (int mt = 0; mt < 4; ++mt) acc[mt] = (f32x4){0.f, 0.f, 0.f, 0.f};
        #pragma unroll
        for (int ks = 0; ks < 6; ++ks) {
            bf16x8 bfr;
            if (PACKED) {
                bfr = *(const bf16x8*)(fqQ + ks * 512);
            } else {
                const float* wpq = wq + (ks * 32 + quad * 8) * 576 + colL;
                #pragma unroll
                for (int j = 0; j < 8; ++j) bfr[j] = (__bf16)wpq[j * 576];
            }
            #pragma unroll
            for (int mt = 0; mt < 4; ++mt) {
                bf16x8 afr = *(const bf16x8*)(REGA + (mt * 16 + l15) * 200 + ks * 32 + quad * 8);
                acc[mt] = __builtin_amdgcn_mfma_f32_16x16x32_bf16(afr, bfr, acc[mt], 0, 0, 0);
            }
        }
        {
            float bv = b_qkv[colL];
            #pragma unroll
            for (int mt = 0; mt < 4; ++mt)
                #pragma unroll
                for (int r = 0; r < 4; ++r)
                    QS[(mt * 16 + quad * 4 + r) * 200 + colL] = f2bf(acc[mt][r] + bv);
        }
        // ---- K tile -> KS
        #pragma unroll
        for (int mt = 0; mt < 4; ++mt) acc[mt] = (f32x4){0.f, 0.f, 0.f, 0.f};
        #pragma unroll
        for (int ks = 0; ks < 6; ++ks) {
            bf16x8 bfr;
            if (PACKED) {
                bfr = *(const bf16x8*)(fqK + ks * 512);
            } else {
                const float* wpq = wq + (ks * 32 + quad * 8) * 576 + 192 + colL;
                #pragma unroll
                for (int j = 0; j < 8; ++j) bfr[j] = (__bf16)wpq[j * 576];
            }
            #pragma unroll
            for (int mt = 0; mt < 4; ++mt) {
                bf16x8 afr = *(const bf16x8*)(REGA + (mt * 16 + l15) * 200 + ks * 32 + quad * 8);
                acc[mt] = __builtin_amdgcn_mfma_f32_16x16x32_bf16(afr, bfr, acc[mt], 0, 0, 0);
            }
        }
        {
            float bv = b_qkv[192 + colL];
            #pragma unroll
            for (int mt = 0; mt < 4; ++mt)
                #pragma unroll
                for (int r = 0; r < 4; ++r)
                    KS[(mt * 16 + quad * 4 + r) * 200 + colL] = f2bf(acc[mt][r] + bv);
        }
        // ---- V tile -> registers (XS still live)
        #pragma unroll
        for (int mt = 0; mt < 4; ++mt) accV[mt] = (f32x4){0.f, 0.f, 0.f, 0.f};
        #pragma unroll
        for (int ks = 0; ks < 6; ++ks) {
            bf16x8 bfr;
            if (PACKED) {
                bfr = *(const bf16x8*)(fqV + ks * 512);
            } else {
                const float* wpq = wq + (ks * 32 + quad * 8) * 576 + 384 + colL;
                #pragma unroll
                for (int j = 0; j < 8; ++j) bfr[j] = (__bf16)wpq[j * 576];
            }
            #pragma unroll
            for (int mt = 0; mt < 4; ++mt) {
                bf16x8 afr = *(const bf16x8*)(REGA + (mt * 16 + l15) * 200 + ks * 32 + quad * 8);
                accV[mt] = __builtin_amdgcn_mfma_f32_16x16x32_bf16(afr, bfr, accV[mt], 0, 0, 0);
            }
        }
    }
    __syncthreads();                                  // bar2: all XS reads done
    // ---- V store transposed over XS: VT[feat][token], stride 64, XOR swizzle.
    {
        float bv = b_qkv[384 + colL];
        #pragma unroll
        for (int mt = 0; mt < 4; ++mt) {
            ushort4 pk;
            pk.x = f2bf(accV[mt][0] + bv);
            pk.y = f2bf(accV[mt][1] + bv);
            pk.z = f2bf(accV[mt][2] + bv);
            pk.w = f2bf(accV[mt][3] + bv);
            int t0 = mt * 16 + quad * 4;
            int g  = (t0 >> 3) ^ (colL & 7);
            *(ushort4*)(REGA + colL * 64 + g * 8 + (t0 & 7)) = pk;
        }
    }
    __syncthreads();                                  // bar3: Q,K,V visible

    // ---- Phase 3a: S = Q Kt * scale + bias, mask, softmax. Wave pair = head.
    const int w  = w2 >> 1;        // head 0..5
    const int mh = (w2 & 1) * 2;   // mt base: 0 or 2 (rows 0..31 / 32..63)
    unsigned short* myP = QS + w2 * 2048;             // P over B+C, 32x64 swz per wave
    float sv[2][4][4];
    {
        const float SCALE = 0.17677669529663687f;     // 32^-0.5
        f32x4 sa[2][4];
        #pragma unroll
        for (int mi = 0; mi < 2; ++mi)
            #pragma unroll
            for (int nt = 0; nt < 4; ++nt) sa[mi][nt] = (f32x4){0.f, 0.f, 0.f, 0.f};
        bf16x8 kf[4];
        #pragma unroll
        for (int nt = 0; nt < 4; ++nt)
            kf[nt] = *(const bf16x8*)(KS + (nt * 16 + l15) * 200 + w * 32 + quad * 8);
        #pragma unroll
        for (int mi = 0; mi < 2; ++mi) {
            bf16x8 afr = *(const bf16x8*)(QS + ((mh + mi) * 16 + l15) * 200 + w * 32 + quad * 8);
            #pragma unroll
            for (int nt = 0; nt < 4; ++nt)
                sa[mi][nt] = __builtin_amdgcn_mfma_f32_16x16x32_bf16(afr, kf[nt], sa[mi][nt], 0, 0, 0);
        }
        __syncthreads();                              // bar4: all QS/KS reads done
        // bias + mask  (C-layout: row = (mh+mi)*16+quad*4+r, col = nt*16+l15)
        const bool mH = (wh == 31), mW = (ww == 31);
        #pragma unroll
        for (int mi = 0; mi < 2; ++mi)
            #pragma unroll
            for (int nt = 0; nt < 4; ++nt)
                #pragma unroll
                for (int r = 0; r < 4; ++r) {
                    int row = (mh + mi) * 16 + quad * 4 + r;
                    int col = nt * 16 + l15;
                    int r1 = row >> 3, c1 = row & 7, r2 = col >> 3, c2 = col & 7;
                    float v = sa[mi][nt][r] * SCALE
                            + (float)RELH[((r1 - r2 + 7) * 15 + (c1 - c2 + 7)) * 6 + w];
                    if ((mH && ((r1 < 4) != (r2 < 4))) || (mW && ((c1 < 4) != (c2 < 4))))
                        v = -1e30f;
                    sv[mi][nt][r] = v;
                }
        // row softmax: each row lives in 4 regs x 16 lanes of one quad-group
        #pragma unroll
        for (int mi = 0; mi < 2; ++mi)
            #pragma unroll
            for (int r = 0; r < 4; ++r) {
                float m = fmaxf(fmaxf(sv[mi][0][r], sv[mi][1][r]),
                                fmaxf(sv[mi][2][r], sv[mi][3][r]));
                m = fmaxf(m, __shfl_xor(m, 1));
                m = fmaxf(m, __shfl_xor(m, 2));
                m = fmaxf(m, __shfl_xor(m, 4));
                m = fmaxf(m, __shfl_xor(m, 8));
                float s = 0.f;
                #pragma unroll
                for (int nt = 0; nt < 4; ++nt) {
                    float p = __expf(sv[mi][nt][r] - m);
                    sv[mi][nt][r] = p;
                    s += p;
                }
                s += __shfl_xor(s, 1);
                s += __shfl_xor(s, 2);
                s += __shfl_xor(s, 4);
                s += __shfl_xor(s, 8);
                float inv = 1.f / s;
                #pragma unroll
                for (int nt = 0; nt < 4; ++nt) sv[mi][nt][r] *= inv;
            }
        // P write (own region, swizzled; writer == reader, no barrier needed)
        #pragma unroll
        for (int mi = 0; mi < 2; ++mi)
            #pragma unroll
            for (int nt = 0; nt < 4; ++nt)
                #pragma unroll
                for (int r = 0; r < 4; ++r) {
                    int row = mi * 16 + quad * 4 + r;          // local 0..31
                    int col = nt * 16 + l15;                   // 0..63
                    myP[row * 64 + (((col >> 3) ^ (row & 7)) << 3) + (col & 7)]
                        = f2bf(sv[mi][nt][r]);
                }
    }

    // ---- Phase 3b: O = P @ V
    {
        f32x4 oa[2][2];
        #pragma unroll
        for (int mi = 0; mi < 2; ++mi) {
            oa[mi][0] = (f32x4){0.f,0.f,0.f,0.f};
            oa[mi][1] = (f32x4){0.f,0.f,0.f,0.f};
        }
        #pragma unroll
        for (int ks2 = 0; ks2 < 2; ++ks2) {
            bf16x8 vf[2];
            #pragma unroll
            for (int nt2 = 0; nt2 < 2; ++nt2) {
                int fr = w * 32 + nt2 * 16 + l15;              // feature row of VT
                int g  = (ks2 * 4 + quad) ^ (fr & 7);
                vf[nt2] = *(const bf16x8*)(REGA + fr * 64 + g * 8);
            }
            #pragma unroll
            for (int mi = 0; mi < 2; ++mi) {
                int row2 = mi * 16 + l15;                      // local P row
                int g2   = (ks2 * 4 + quad) ^ (row2 & 7);
                bf16x8 pf = *(const bf16x8*)(myP + row2 * 64 + g2 * 8);
                #pragma unroll
                for (int nt2 = 0; nt2 < 2; ++nt2)
                    oa[mi][nt2] = __builtin_amdgcn_mfma_f32_16x16x32_bf16(pf, vf[nt2], oa[mi][nt2], 0, 0, 0);
            }
        }
        __syncthreads();                              // bar5: all VT reads done
        unsigned short* OS = REGA;                    // O over VT region, 64x200
        #pragma unroll
        for (int mi = 0; mi < 2; ++mi)
            #pragma unroll
            for (int nt2 = 0; nt2 < 2; ++nt2)
                #pragma unroll
                for (int r = 0; r < 4; ++r)
                    OS[((mh + mi) * 16 + quad * 4 + r) * 200 + w * 32 + nt2 * 16 + l15]
                        = f2bf(oa[mi][nt2][r]);
    }
    __syncthreads();                                  // bar6: O visible

    // ---- Phase 4: out = OS @ w_lin + b_lin, inverse roll, fp32 store
    {
        const unsigned short* OS = REGA;
        int ntg = w2;                                  // 0..11, one col-tile per wave
        const unsigned short* fl = wp + 110592 + ntg * 3072 + lane * 8;
        f32x4 acc[4];
        #pragma unroll
        for (int mt = 0; mt < 4; ++mt) acc[mt] = (f32x4){0.f, 0.f, 0.f, 0.f};
        #pragma unroll
        for (int ks = 0; ks < 6; ++ks) {
            bf16x8 bfr;
            if (PACKED) {
                bfr = *(const bf16x8*)(fl + ks * 512);
            } else {
                const float* wpq = wl + (ks * 32 + quad * 8) * 192 + ntg * 16 + l15;
                #pragma unroll
                for (int j = 0; j < 8; ++j) bfr[j] = (__bf16)wpq[j * 192];
            }
            #pragma unroll
            for (int mt = 0; mt < 4; ++mt) {
                bf16x8 afr = *(const bf16x8*)(OS + (mt * 16 + l15) * 200 + ks * 32 + quad * 8);
                acc[mt] = __builtin_amdgcn_mfma_f32_16x16x32_bf16(afr, bfr, acc[mt], 0, 0, 0);
            }
        }
        int col  = ntg * 16 + l15;                     // 0..191
        float bv = b_lin[col];
        #pragma unroll
        for (int mt = 0; mt < 4; ++mt)
            #pragma unroll
            for (int r = 0; r < 4; ++r) {
                int row = mt * 16 + quad * 4 + r;
                int hs = wh * 8 + (row >> 3), wsx = ww * 8 + (row & 7);
                int ho = (hs + 4) & 255,      wo  = (wsx + 4) & 255;
                out[((((b << 8) + ho) << 8) + wo) * 192 + col] = acc[mt][r] + bv;
            }
    }
}

// ---------------------------------------------------------------------------
extern "C" void kernel_launch(void* const* d_in, const int* in_sizes, int n_in,
                              void* d_out, int out_size, void* d_ws, size_t ws_size,
                              hipStream_t stream) {
    const float* x  = (const float*)d_in[0];   // [4,256,256,192] fp32
    const float* wq = (const float*)d_in[1];   // [192,576]
    const float* bq = (const float*)d_in[2];   // [576]
    const float* wl = (const float*)d_in[3];   // [192,192]
    const float* bl = (const float*)d_in[4];   // [192]
    const float* rp = (const float*)d_in[5];   // [225,6]
    (void)in_sizes; (void)n_in;

    if (ws_size >= 294912 && d_ws != nullptr) {
        unsigned short* wpk = (unsigned short*)d_ws;
        pack_w<<<576, 256, 0, stream>>>(wq, wl, wpk);
        wmsa_fused<true><<<4096, 768, 0, stream>>>(x, wq, bq, wl, bl, rp, wpk, (float*)d_out);
    } else {
        wmsa_fused<false><<<4096, 768, 0, stream>>>(x, wq, bq, wl, bl, rp, nullptr, (float*)d_out);
    }
}